// Round 6
// baseline (45441.809 us; speedup 1.0000x reference)
//
#include <hip/hip_runtime.h>
#include <hip/hip_bf16.h>

#define NSL 64
#define NPX 16384   // 128*128
#define VN  2097152 // 128^3

// ---------------- prep: per-slice R,t (fp32 inputs) ----------------
__global__ void k_prep(const float* __restrict__ tr, const float* __restrict__ psf,
                       float* __restrict__ Rm, float* __restrict__ pw)
{
  int n = threadIdx.x;
  if (n < 27) pw[n] = psf[n];
  if (n >= NSL) return;
  #pragma unroll
  for (int i = 0; i < 3; i++){
    #pragma unroll
    for (int j = 0; j < 3; j++) Rm[n*12 + i*3 + j] = tr[n*12 + i*4 + j];
    Rm[n*12 + 9 + i] = tr[n*12 + i*4 + 3];
  }
}

// ---------------- mask: blur(slices)>0 == any 3x3 neighbor > 0 ----------------
__global__ void k_mask(const float* __restrict__ slices, float* __restrict__ mask)
{
  int gid = blockIdx.x*256 + threadIdx.x;
  if (gid >= NSL*NPX) return;
  int n = gid >> 14, p = gid & 16383;
  int py = p >> 7, px = p & 127;
  const float* s = slices + n*NPX;
  bool any = false;
  for (int dy = -1; dy <= 1; dy++){
    int yy = py + dy;
    if ((unsigned)yy >= 128u) continue;
    for (int dx = -1; dx <= 1; dx++){
      int xx = px + dx;
      if ((unsigned)xx >= 128u) continue;
      any = any || (s[yy*128 + xx] > 0.f);
    }
  }
  mask[gid] = any ? 1.f : 0.f;
}

__global__ void k_volcopy(const float* __restrict__ v, float* __restrict__ o)
{
  int gid = blockIdx.x*256 + threadIdx.x;
  if (gid < VN) o[gid] = v[gid];
}

__global__ void k_copy0(const float* __restrict__ slices, float* __restrict__ z)
{
  int gid = blockIdx.x*256 + threadIdx.x;
  if (gid >= NSL*NPX) return;
  int n = gid >> 14, p = gid & 16383;
  z[n*2*NPX + p] = slices[gid];
}

// ---------------- trilinear helpers ----------------
__device__ __forceinline__ float tri_gather(const float* __restrict__ vol, float x, float y, float z)
{
  float xf = floorf(x), yf = floorf(y), zf = floorf(z);
  int x0 = (int)xf, y0 = (int)yf, z0 = (int)zf;
  float fx = x - xf, fy = y - yf, fz = z - zf;
  float gx0 = 1.f - fx, gy0 = 1.f - fy, gz0 = 1.f - fz;
  bool vx0 = (unsigned)x0 < 128u, vx1 = (unsigned)(x0+1) < 128u;
  bool vy0 = (unsigned)y0 < 128u, vy1 = (unsigned)(y0+1) < 128u;
  bool vz0 = (unsigned)z0 < 128u, vz1 = (unsigned)(z0+1) < 128u;
  int i0 = (z0*128 + y0)*128 + x0;
  float acc = 0.f;
  if (vz0){
    if (vy0){
      if (vx0) acc += gx0*gy0*gz0 * vol[i0];
      if (vx1) acc += fx *gy0*gz0 * vol[i0+1];
    }
    if (vy1){
      if (vx0) acc += gx0*fy*gz0 * vol[i0+128];
      if (vx1) acc += fx *fy*gz0 * vol[i0+129];
    }
  }
  if (vz1){
    int i1 = i0 + 16384;
    if (vy0){
      if (vx0) acc += gx0*gy0*fz * vol[i1];
      if (vx1) acc += fx *gy0*fz * vol[i1+1];
    }
    if (vy1){
      if (vx0) acc += gx0*fy*fz * vol[i1+128];
      if (vx1) acc += fx *fy*fz * vol[i1+129];
    }
  }
  return acc;
}

__device__ __forceinline__ void tri_scatter(float* __restrict__ vol, float x, float y, float z, float val)
{
  float xf = floorf(x), yf = floorf(y), zf = floorf(z);
  int x0 = (int)xf, y0 = (int)yf, z0 = (int)zf;
  float fx = x - xf, fy = y - yf, fz = z - zf;
  float gx0 = 1.f - fx, gy0 = 1.f - fy, gz0 = 1.f - fz;
  bool vx0 = (unsigned)x0 < 128u, vx1 = (unsigned)(x0+1) < 128u;
  bool vy0 = (unsigned)y0 < 128u, vy1 = (unsigned)(y0+1) < 128u;
  bool vz0 = (unsigned)z0 < 128u, vz1 = (unsigned)(z0+1) < 128u;
  int i0 = (z0*128 + y0)*128 + x0;
  if (vz0){
    if (vy0){
      if (vx0) atomicAdd(&vol[i0],     gx0*gy0*gz0*val);
      if (vx1) atomicAdd(&vol[i0+1],   fx *gy0*gz0*val);
    }
    if (vy1){
      if (vx0) atomicAdd(&vol[i0+128], gx0*fy*gz0*val);
      if (vx1) atomicAdd(&vol[i0+129], fx *fy*gz0*val);
    }
  }
  if (vz1){
    int i1 = i0 + 16384;
    if (vy0){
      if (vx0) atomicAdd(&vol[i1],     gx0*gy0*fz*val);
      if (vx1) atomicAdd(&vol[i1+1],   fx *gy0*fz*val);
    }
    if (vy1){
      if (vx0) atomicAdd(&vol[i1+128], gx0*fy*fz*val);
      if (vx1) atomicAdd(&vol[i1+129], fx *fy*fz*val);
    }
  }
}

// ---------------- A: gather over 27 PSF taps ----------------
__global__ void k_gather(const float* __restrict__ vol, const float* __restrict__ Rm,
                         const float* __restrict__ pw, const float* __restrict__ mask,
                         const float* __restrict__ ps, float* __restrict__ out,
                         int outStride, int outOff)
{
  int gid = blockIdx.x*256 + threadIdx.x;
  if (gid >= NSL*NPX) return;
  int n = gid >> 14, p = gid & 16383;
  int py = p >> 7, px = p & 127;
  float rm[12];
  #pragma unroll
  for (int i = 0; i < 12; i++) rm[i] = Rm[n*12 + i];
  float gx = (float)px - 63.5f, gy = (float)py - 63.5f;
  float bx = rm[0]*gx + rm[1]*gy + rm[9]  + 63.5f;
  float by = rm[3]*gx + rm[4]*gy + rm[10] + 63.5f;
  float bz = rm[6]*gx + rm[7]*gy + rm[11] + 63.5f;
  float acc = 0.f;
  #pragma unroll 1
  for (int k = 0; k < 27; k++){
    float ox = (float)(k % 3) - 1.f;
    float oy = (float)((k/3) % 3) - 1.f;
    float oz = (float)(k/9) - 1.f;
    float dx = rm[0]*ox + rm[1]*oy + rm[2]*oz;
    float dy = rm[3]*ox + rm[4]*oy + rm[5]*oz;
    float dz = rm[6]*ox + rm[7]*oy + rm[8]*oz;
    acc += pw[k] * tri_gather(vol, bx + dx, by + dy, bz + dz);
  }
  float v = acc * mask[gid];
  if (ps) v *= ps[n];
  out[n*outStride + outOff + p] = v;
}

// ---------------- At: scatter over 27 PSF taps ----------------
__global__ void k_scatter(float* __restrict__ volOut, const float* __restrict__ s,
                          const float* __restrict__ Rm, const float* __restrict__ pw,
                          const float* __restrict__ mask, const float* __restrict__ ps)
{
  int gid = blockIdx.x*256 + threadIdx.x;
  if (gid >= NSL*NPX) return;
  int n = gid >> 14, p = gid & 16383;
  float val = s[gid] * mask[gid];
  if (ps) val *= ps[n];
  if (val == 0.f) return;
  int py = p >> 7, px = p & 127;
  float rm[12];
  #pragma unroll
  for (int i = 0; i < 12; i++) rm[i] = Rm[n*12 + i];
  float gx = (float)px - 63.5f, gy = (float)py - 63.5f;
  float bx = rm[0]*gx + rm[1]*gy + rm[9]  + 63.5f;
  float by = rm[3]*gx + rm[4]*gy + rm[10] + 63.5f;
  float bz = rm[6]*gx + rm[7]*gy + rm[11] + 63.5f;
  #pragma unroll 1
  for (int k = 0; k < 27; k++){
    float ox = (float)(k % 3) - 1.f;
    float oy = (float)((k/3) % 3) - 1.f;
    float oz = (float)(k/9) - 1.f;
    float dx = rm[0]*ox + rm[1]*oy + rm[2]*oz;
    float dy = rm[3]*ox + rm[4]*oy + rm[5]*oz;
    float dz = rm[6]*ox + rm[7]*oy + rm[8]*oz;
    tri_scatter(volOut, bx + dx, by + dy, bz + dz, pw[k]*val);
  }
}

// ---------------- direct conv (NCHW fp32) ----------------
template<int K>
__global__ void k_conv(const float* __restrict__ in, const float* __restrict__ wt,
                       const float* __restrict__ res, float* __restrict__ out,
                       int Cin, int Hin, int Win, int Cout, int Hout, int Wout,
                       int stride, int pad, int dorelu, int total)
{
  int gid = blockIdx.x*blockDim.x + threadIdx.x;
  if (gid >= total) return;
  int w4 = Wout >> 2;
  int t = gid;
  int x4 = (t % w4) << 2; t /= w4;
  int oy = t % Hout; t /= Hout;
  int co2 = Cout >> 1;
  int co = (t % co2) << 1; int b = t / co2;

  float acc0[4] = {0.f,0.f,0.f,0.f};
  float acc1[4] = {0.f,0.f,0.f,0.f};
  for (int ci = 0; ci < Cin; ci++){
    const float* ip  = in + (size_t)((b*Cin + ci)*Hin)*Win;
    const float* wp0 = wt + (size_t)(co*Cin + ci)*K*K;
    const float* wp1 = wt + (size_t)((co+1)*Cin + ci)*K*K;
    #pragma unroll
    for (int kh = 0; kh < K; kh++){
      int iy = oy*stride + kh - pad;
      if ((unsigned)iy >= (unsigned)Hin) continue;
      const float* rowp = ip + iy*Win;
      #pragma unroll
      for (int kw = 0; kw < K; kw++){
        float w0 = wp0[kh*K+kw];
        float w1 = wp1[kh*K+kw];
        #pragma unroll
        for (int j = 0; j < 4; j++){
          int ix = (x4+j)*stride + kw - pad;
          if ((unsigned)ix < (unsigned)Win){
            float v = rowp[ix];
            acc0[j] += v*w0;
            acc1[j] += v*w1;
          }
        }
      }
    }
  }
  size_t ob = ((size_t)(b*Cout + co)*Hout + oy)*Wout + x4;
  size_t ostep = (size_t)Hout*Wout;
  #pragma unroll
  for (int j = 0; j < 4; j++){
    float v0 = acc0[j], v1 = acc1[j];
    if (res){ v0 += res[ob + j]; v1 += res[ob + ostep + j]; }
    if (dorelu){ v0 = fmaxf(v0, 0.f); v1 = fmaxf(v1, 0.f); }
    out[ob + j] = v0;
    out[ob + ostep + j] = v1;
  }
}

// ---------------- pool + transformer ----------------
__global__ void k_pool(const float* __restrict__ in, float* __restrict__ feat, int cnt)
{
  int gid = blockIdx.x*256 + threadIdx.x;
  if (gid >= cnt) return;
  const float* p = in + (size_t)gid*256;
  float s = 0.f;
  for (int i = 0; i < 256; i++) s += p[i];
  feat[gid] = s * (1.f/256.f);
}

__global__ void k_pe(const float* __restrict__ feat, const float* __restrict__ theta,
                     const float* __restrict__ idxin, const float* __restrict__ pos_w,
                     const float* __restrict__ pos_b, float* __restrict__ hs)
{
  int gid = blockIdx.x*256 + threadIdx.x;
  if (gid >= 64*256) return;
  int n = gid >> 8, d = gid & 255;
  float s = pos_b[d];
  #pragma unroll
  for (int j = 0; j < 6; j++) s += theta[n*6+j] * pos_w[j*256+d];
  #pragma unroll
  for (int j = 0; j < 2; j++) s += idxin[n*2+j] * pos_w[(6+j)*256+d];
  hs[gid] = feat[gid] + s;
}

__global__ void k_qkv(const float* __restrict__ hs, const float* __restrict__ wq,
                      const float* __restrict__ wk, const float* __restrict__ wv,
                      float* __restrict__ qkv)
{
  int gid = blockIdx.x*256 + threadIdx.x;
  if (gid >= 64*768) return;
  int n = gid / 768, m = gid % 768;
  int which = m >> 8, j = m & 255;
  const float* w = (which == 0) ? wq : (which == 1) ? wk : wv;
  const float* h = hs + n*256;
  float s = 0.f;
  for (int i = 0; i < 256; i++) s += h[i] * w[i*256 + j];
  qkv[which*16384 + n*256 + j] = s;
}

__global__ void k_attn(const float* __restrict__ qkv, float* __restrict__ aout)
{
  int h = blockIdx.x;
  int tid = threadIdx.x;
  __shared__ float sc[4096];
  const float* q  = qkv + h*64;
  const float* kk = qkv + 16384 + h*64;
  const float* v  = qkv + 32768 + h*64;
  for (int idx = tid; idx < 4096; idx += 256){
    int qi = idx >> 6, ki = idx & 63;
    float s = 0.f;
    for (int d = 0; d < 64; d++) s += q[qi*256+d] * kk[ki*256+d];
    sc[idx] = s * 0.125f;
  }
  __syncthreads();
  if (tid < 64){
    float mx = -1e30f;
    for (int k = 0; k < 64; k++) mx = fmaxf(mx, sc[tid*64+k]);
    float sum = 0.f;
    for (int k = 0; k < 64; k++){ float e = __expf(sc[tid*64+k]-mx); sc[tid*64+k] = e; sum += e; }
    float inv = 1.f/sum;
    for (int k = 0; k < 64; k++) sc[tid*64+k] *= inv;
  }
  __syncthreads();
  for (int idx = tid; idx < 4096; idx += 256){
    int qi = idx >> 6, d = idx & 63;
    float s = 0.f;
    for (int ki = 0; ki < 64; ki++) s += sc[qi*64+ki] * v[ki*256+d];
    aout[qi*256 + h*64 + d] = s;
  }
}

__global__ void k_proj_ln(const float* __restrict__ ain, const float* __restrict__ wo,
                          const float* __restrict__ g, const float* __restrict__ bb,
                          float* __restrict__ hs)
{
  int n = blockIdx.x, d = threadIdx.x;
  __shared__ float row[256];
  __shared__ float red[256];
  __shared__ float smean, svar;
  row[d] = ain[n*256+d];
  __syncthreads();
  float s = hs[n*256+d];
  for (int i = 0; i < 256; i++) s += row[i] * wo[i*256+d];
  red[d] = s; __syncthreads();
  for (int off = 128; off; off >>= 1){ if (d < off) red[d] += red[d+off]; __syncthreads(); }
  if (d == 0) smean = red[0] * (1.f/256.f);
  __syncthreads();
  float c = s - smean;
  red[d] = c*c; __syncthreads();
  for (int off = 128; off; off >>= 1){ if (d < off) red[d] += red[d+off]; __syncthreads(); }
  if (d == 0) svar = red[0] * (1.f/256.f);
  __syncthreads();
  hs[n*256+d] = c * rsqrtf(svar + 1e-5f) * g[d] + bb[d];
}

__global__ void k_ff1(const float* __restrict__ hs, const float* __restrict__ w,
                      const float* __restrict__ b, float* __restrict__ h1)
{
  int gid = blockIdx.x*256 + threadIdx.x;
  if (gid >= 64*512) return;
  int n = gid >> 9, j = gid & 511;
  float s = b[j];
  const float* h = hs + n*256;
  for (int i = 0; i < 256; i++) s += h[i] * w[i*512 + j];
  h1[gid] = fmaxf(s, 0.f);
}

__global__ void k_ff2_ln(const float* __restrict__ h1, const float* __restrict__ w,
                         const float* __restrict__ b, const float* __restrict__ g,
                         const float* __restrict__ bb, float* __restrict__ hs)
{
  int n = blockIdx.x, d = threadIdx.x;
  __shared__ float row[512];
  __shared__ float red[256];
  __shared__ float smean, svar;
  row[d] = h1[n*512+d];
  row[d+256] = h1[n*512+256+d];
  __syncthreads();
  float s = hs[n*256+d] + b[d];
  for (int i = 0; i < 512; i++) s += row[i] * w[i*256+d];
  red[d] = s; __syncthreads();
  for (int off = 128; off; off >>= 1){ if (d < off) red[d] += red[d+off]; __syncthreads(); }
  if (d == 0) smean = red[0] * (1.f/256.f);
  __syncthreads();
  float c = s - smean;
  red[d] = c*c; __syncthreads();
  for (int off = 128; off; off >>= 1){ if (d < off) red[d] += red[d+off]; __syncthreads(); }
  if (d == 0) svar = red[0] * (1.f/256.f);
  __syncthreads();
  hs[n*256+d] = c * rsqrtf(svar + 1e-5f) * g[d] + bb[d];
}

__global__ void k_head(const float* __restrict__ hs, const float* __restrict__ fcw,
                       const float* __restrict__ fcb, float* __restrict__ pvec,
                       float* __restrict__ outx)
{
  int n = threadIdx.x; // 64 threads
  float s = fcb[0];
  const float* h = hs + n*256;
  for (int i = 0; i < 256; i++) s += h[i] * fcw[i];
  __shared__ float xs[64];
  xs[n] = s;
  __syncthreads();
  float mx = -1e30f;
  for (int i = 0; i < 64; i++) mx = fmaxf(mx, xs[i]);
  float sum = 0.f;
  for (int i = 0; i < 64; i++) sum += __expf(xs[i]-mx);
  float val = __expf(s-mx)/sum * 64.f;
  val = fminf(val, 3.f);
  pvec[n] = val;
  outx[n] = val;          // fp32 output!
}

// ---------------- CG helpers ----------------
__global__ void k_dot(const float* __restrict__ a, const float* __restrict__ b,
                      float* __restrict__ scal, int slot, int n)
{
  int gid = blockIdx.x*blockDim.x + threadIdx.x;
  int stride = gridDim.x*blockDim.x;
  float s = 0.f;
  for (int i = gid; i < n; i += stride) s += a[i]*b[i];
  for (int off = 32; off; off >>= 1) s += __shfl_down(s, off, 64);
  __shared__ float wsum[4];
  int lane = threadIdx.x & 63, wv = threadIdx.x >> 6;
  if (lane == 0) wsum[wv] = s;
  __syncthreads();
  if (threadIdx.x == 0) atomicAdd(&scal[slot], wsum[0]+wsum[1]+wsum[2]+wsum[3]);
}

__global__ void k_div(float* scal, int so, int sa, int sb)
{
  if (threadIdx.x == 0 && blockIdx.x == 0) scal[so] = scal[sa] / scal[sb];
}

__global__ void k_rinit(const float* __restrict__ b, const float* __restrict__ A,
                        float* __restrict__ r, float* __restrict__ p)
{
  int gid = blockIdx.x*256 + threadIdx.x;
  if (gid < VN){ float v = b[gid] - A[gid]; r[gid] = v; p[gid] = v; }
}

__global__ void k_xr(float* __restrict__ x, const float* __restrict__ p,
                     float* __restrict__ r, const float* __restrict__ Ap,
                     const float* __restrict__ scal, int slot)
{
  int gid = blockIdx.x*256 + threadIdx.x;
  if (gid < VN){
    float a = scal[slot];
    x[gid] += a * p[gid];
    r[gid] -= a * Ap[gid];
  }
}

__global__ void k_pupd(float* __restrict__ p, const float* __restrict__ r,
                       const float* __restrict__ scal, int slot)
{
  int gid = blockIdx.x*256 + threadIdx.x;
  if (gid < VN){ float b = scal[slot]; p[gid] = r[gid] + b * p[gid]; }
}

__global__ void k_xonly(float* __restrict__ x, const float* __restrict__ p,
                        const float* __restrict__ scal, int slot)
{
  int gid = blockIdx.x*256 + threadIdx.x;
  if (gid < VN) x[gid] += scal[slot] * p[gid];
}

__global__ void k_final(const float* __restrict__ x, float* __restrict__ out)
{
  int gid = blockIdx.x*256 + threadIdx.x;
  if (gid < VN) out[gid] = fmaxf(x[gid], 0.f);   // fp32 output!
}

// ---------------- host launch ----------------
extern "C" void kernel_launch(void* const* d_in, const int* in_sizes, int n_in,
                              void* d_out, int out_size, void* d_ws, size_t ws_size,
                              hipStream_t stream)
{
  const float* theta      = (const float*)d_in[0];
  const float* transforms = (const float*)d_in[1];
  const float* slices     = (const float*)d_in[2];
  const float* volume     = (const float*)d_in[3];
  const float* psf        = (const float*)d_in[4];
  const float* idxv       = (const float*)d_in[5];

  char* wsp = (char*)d_ws;
  auto carve = [&](size_t bytes)->void*{
    void* r = (void*)wsp; wsp += (bytes + 255) & ~(size_t)255; return r;
  };
  float* scal = (float*)carve(16*4);
  float* Rm   = (float*)carve(768*4);
  float* pw   = (float*)carve(32*4);
  float* pvec = (float*)carve(64*4);
  float* feat = (float*)carve(16384*4);
  float* hs   = (float*)carve(16384*4);
  float* qkv  = (float*)carve(49152*4);
  float* aout = (float*)carve(16384*4);
  float* h1   = (float*)carve(32768*4);
  float* mask = (float*)carve((size_t)NSL*NPX*4);
  float* volA = (float*)carve((size_t)VN*4);
  // union (36.25 MB): CNN {z,bufA,bufB,bufC} / CG {bvol,rvol,pvol,Avol}+sscr
  float* U    = (float*)carve((size_t)(4*VN + NSL*NPX)*4);
  float* z    = U;                float* bvol = U;
  float* bufA = U + VN;           float* rvol = U + VN;
  float* bufB = U + 2*(size_t)VN; float* pvol = U + 2*(size_t)VN;
  float* bufC = U + 3*(size_t)VN; float* Avol = U + 3*(size_t)VN;
  float* sscr = U + 4*(size_t)VN;

  hipMemsetAsync(scal, 0, 64, stream);
  k_prep<<<1, 64, 0, stream>>>(transforms, psf, Rm, pw);
  k_mask<<<4096, 256, 0, stream>>>(slices, mask);
  k_volcopy<<<8192, 256, 0, stream>>>(volume, volA);
  // slices_est -> z ch1 (masked); slices -> z ch0
  k_gather<<<4096, 256, 0, stream>>>(volA, Rm, pw, mask, nullptr, z, 2*NPX, NPX);
  k_copy0<<<4096, 256, 0, stream>>>(slices, z);

  // CNN: 8 chunks of 8 slices, fp32 activations
  for (int c = 0; c < 8; c++){
    const float* zc = z + (size_t)c*8*2*NPX;
    k_conv<7><<<1024, 256, 0, stream>>>(zc,   (const float*)d_in[6],  nullptr, bufA, 2, 128, 128, 64, 64, 64, 2, 2, 1, 262144);
    k_conv<3><<<1024, 256, 0, stream>>>(bufA, (const float*)d_in[7],  nullptr, bufB, 64, 64, 64, 64, 64, 64, 1, 1, 1, 262144);
    k_conv<3><<<1024, 256, 0, stream>>>(bufB, (const float*)d_in[8],  bufA,    bufC, 64, 64, 64, 64, 64, 64, 1, 1, 1, 262144);
    k_conv<3><<<512, 256, 0, stream>>>(bufC,  (const float*)d_in[9],  nullptr, bufA, 64, 64, 64, 128, 32, 32, 2, 0, 1, 131072);
    k_conv<1><<<512, 256, 0, stream>>>(bufC,  (const float*)d_in[11], nullptr, bufB, 64, 64, 64, 128, 32, 32, 2, 0, 0, 131072);
    k_conv<3><<<512, 256, 0, stream>>>(bufA,  (const float*)d_in[10], bufB,    bufC, 128, 32, 32, 128, 32, 32, 1, 1, 1, 131072);
    k_conv<3><<<256, 256, 0, stream>>>(bufC,  (const float*)d_in[12], nullptr, bufA, 128, 32, 32, 256, 16, 16, 2, 0, 1, 65536);
    k_conv<1><<<256, 256, 0, stream>>>(bufC,  (const float*)d_in[14], nullptr, bufB, 128, 32, 32, 256, 16, 16, 2, 0, 0, 65536);
    k_conv<3><<<256, 256, 0, stream>>>(bufA,  (const float*)d_in[13], bufB,    bufC, 256, 16, 16, 256, 16, 16, 1, 1, 1, 65536);
    k_pool<<<8, 256, 0, stream>>>(bufC, feat + (size_t)c*8*256, 2048);
  }

  k_pe<<<64, 256, 0, stream>>>(feat, theta, idxv, (const float*)d_in[15], (const float*)d_in[16], hs);
  for (int l = 0; l < 4; l++){
    k_qkv<<<192, 256, 0, stream>>>(hs, (const float*)d_in[17] + (size_t)l*65536,
                                       (const float*)d_in[18] + (size_t)l*65536,
                                       (const float*)d_in[19] + (size_t)l*65536, qkv);
    k_attn<<<4, 256, 0, stream>>>(qkv, aout);
    k_proj_ln<<<64, 256, 0, stream>>>(aout, (const float*)d_in[20] + (size_t)l*65536,
                                      (const float*)d_in[21] + l*256, (const float*)d_in[22] + l*256, hs);
    k_ff1<<<128, 256, 0, stream>>>(hs, (const float*)d_in[23] + (size_t)l*131072,
                                   (const float*)d_in[24] + l*512, h1);
    k_ff2_ln<<<64, 256, 0, stream>>>(h1, (const float*)d_in[25] + (size_t)l*131072,
                                     (const float*)d_in[26] + l*256, (const float*)d_in[27] + l*256,
                                     (const float*)d_in[28] + l*256, hs);
  }
  k_head<<<1, 64, 0, stream>>>(hs, (const float*)d_in[29], (const float*)d_in[30], pvec,
                               (float*)d_out + VN);

  // ---- CG (union region now CG-owned) ----
  hipMemsetAsync(bvol, 0, (size_t)VN*4, stream);
  k_scatter<<<4096, 256, 0, stream>>>(bvol, slices, Rm, pw, mask, pvec);      // b = At(slices*p)
  k_gather<<<4096, 256, 0, stream>>>(volA, Rm, pw, mask, pvec, sscr, NPX, 0); // A(x0)*mask*p
  hipMemsetAsync(Avol, 0, (size_t)VN*4, stream);
  k_scatter<<<4096, 256, 0, stream>>>(Avol, sscr, Rm, pw, mask, nullptr);     // AtA(x0)
  k_rinit<<<8192, 256, 0, stream>>>(bvol, Avol, rvol, pvol);
  k_dot<<<512, 256, 0, stream>>>(rvol, rvol, scal, 0, VN);         // rr0
  // iter 1
  k_gather<<<4096, 256, 0, stream>>>(pvol, Rm, pw, mask, pvec, sscr, NPX, 0);
  hipMemsetAsync(Avol, 0, (size_t)VN*4, stream);
  k_scatter<<<4096, 256, 0, stream>>>(Avol, sscr, Rm, pw, mask, nullptr);
  k_dot<<<512, 256, 0, stream>>>(pvol, Avol, scal, 1, VN);         // pAp1
  k_div<<<1, 1, 0, stream>>>(scal, 2, 0, 1);                       // alpha1 = rr0/pAp1
  k_xr<<<8192, 256, 0, stream>>>(volA, pvol, rvol, Avol, scal, 2);
  k_dot<<<512, 256, 0, stream>>>(rvol, rvol, scal, 3, VN);         // rr1
  k_div<<<1, 1, 0, stream>>>(scal, 4, 3, 0);                       // beta = rr1/rr0
  k_pupd<<<8192, 256, 0, stream>>>(pvol, rvol, scal, 4);
  // iter 2
  k_gather<<<4096, 256, 0, stream>>>(pvol, Rm, pw, mask, pvec, sscr, NPX, 0);
  hipMemsetAsync(Avol, 0, (size_t)VN*4, stream);
  k_scatter<<<4096, 256, 0, stream>>>(Avol, sscr, Rm, pw, mask, nullptr);
  k_dot<<<512, 256, 0, stream>>>(pvol, Avol, scal, 5, VN);         // pAp2
  k_div<<<1, 1, 0, stream>>>(scal, 6, 3, 5);                       // alpha2 = rr1/pAp2
  k_xonly<<<8192, 256, 0, stream>>>(volA, pvol, scal, 6);

  k_final<<<8192, 256, 0, stream>>>(volA, (float*)d_out);
}

// Round 7
// 19366.513 us; speedup vs baseline: 2.3464x; 2.3464x over previous
//
#include <hip/hip_runtime.h>
#include <hip/hip_bf16.h>

#define NSL 64
#define NPX 16384   // 128*128
#define VN  2097152 // 128^3

// ---------------- prep: per-slice R,t (fp32 inputs) ----------------
__global__ void k_prep(const float* __restrict__ tr, const float* __restrict__ psf,
                       float* __restrict__ Rm, float* __restrict__ pw)
{
  int n = threadIdx.x;
  if (n < 27) pw[n] = psf[n];
  if (n >= NSL) return;
  #pragma unroll
  for (int i = 0; i < 3; i++){
    #pragma unroll
    for (int j = 0; j < 3; j++) Rm[n*12 + i*3 + j] = tr[n*12 + i*4 + j];
    Rm[n*12 + 9 + i] = tr[n*12 + i*4 + 3];
  }
}

// ---------------- mask ----------------
__global__ void k_mask(const float* __restrict__ slices, float* __restrict__ mask)
{
  int gid = blockIdx.x*256 + threadIdx.x;
  if (gid >= NSL*NPX) return;
  int n = gid >> 14, p = gid & 16383;
  int py = p >> 7, px = p & 127;
  const float* s = slices + n*NPX;
  bool any = false;
  for (int dy = -1; dy <= 1; dy++){
    int yy = py + dy;
    if ((unsigned)yy >= 128u) continue;
    for (int dx = -1; dx <= 1; dx++){
      int xx = px + dx;
      if ((unsigned)xx >= 128u) continue;
      any = any || (s[yy*128 + xx] > 0.f);
    }
  }
  mask[gid] = any ? 1.f : 0.f;
}

__global__ void k_volcopy(const float* __restrict__ v, float* __restrict__ o)
{
  int gid = blockIdx.x*256 + threadIdx.x;
  if (gid < VN) o[gid] = v[gid];
}

__global__ void k_copy0(const float* __restrict__ slices, float* __restrict__ z)
{
  int gid = blockIdx.x*256 + threadIdx.x;
  if (gid >= NSL*NPX) return;
  int n = gid >> 14, p = gid & 16383;
  z[n*2*NPX + p] = slices[gid];
}

// ---------------- trilinear helpers ----------------
__device__ __forceinline__ float tri_gather(const float* __restrict__ vol, float x, float y, float z)
{
  float xf = floorf(x), yf = floorf(y), zf = floorf(z);
  int x0 = (int)xf, y0 = (int)yf, z0 = (int)zf;
  float fx = x - xf, fy = y - yf, fz = z - zf;
  float gx0 = 1.f - fx, gy0 = 1.f - fy, gz0 = 1.f - fz;
  bool vx0 = (unsigned)x0 < 128u, vx1 = (unsigned)(x0+1) < 128u;
  bool vy0 = (unsigned)y0 < 128u, vy1 = (unsigned)(y0+1) < 128u;
  bool vz0 = (unsigned)z0 < 128u, vz1 = (unsigned)(z0+1) < 128u;
  int i0 = (z0*128 + y0)*128 + x0;
  float acc = 0.f;
  if (vz0){
    if (vy0){
      if (vx0) acc += gx0*gy0*gz0 * vol[i0];
      if (vx1) acc += fx *gy0*gz0 * vol[i0+1];
    }
    if (vy1){
      if (vx0) acc += gx0*fy*gz0 * vol[i0+128];
      if (vx1) acc += fx *fy*gz0 * vol[i0+129];
    }
  }
  if (vz1){
    int i1 = i0 + 16384;
    if (vy0){
      if (vx0) acc += gx0*gy0*fz * vol[i1];
      if (vx1) acc += fx *gy0*fz * vol[i1+1];
    }
    if (vy1){
      if (vx0) acc += gx0*fy*fz * vol[i1+128];
      if (vx1) acc += fx *fy*fz * vol[i1+129];
    }
  }
  return acc;
}

__device__ __forceinline__ void tri_scatter(float* __restrict__ vol, float x, float y, float z, float val)
{
  float xf = floorf(x), yf = floorf(y), zf = floorf(z);
  int x0 = (int)xf, y0 = (int)yf, z0 = (int)zf;
  float fx = x - xf, fy = y - yf, fz = z - zf;
  float gx0 = 1.f - fx, gy0 = 1.f - fy, gz0 = 1.f - fz;
  bool vx0 = (unsigned)x0 < 128u, vx1 = (unsigned)(x0+1) < 128u;
  bool vy0 = (unsigned)y0 < 128u, vy1 = (unsigned)(y0+1) < 128u;
  bool vz0 = (unsigned)z0 < 128u, vz1 = (unsigned)(z0+1) < 128u;
  int i0 = (z0*128 + y0)*128 + x0;
  if (vz0){
    if (vy0){
      if (vx0) atomicAdd(&vol[i0],     gx0*gy0*gz0*val);
      if (vx1) atomicAdd(&vol[i0+1],   fx *gy0*gz0*val);
    }
    if (vy1){
      if (vx0) atomicAdd(&vol[i0+128], gx0*fy*gz0*val);
      if (vx1) atomicAdd(&vol[i0+129], fx *fy*gz0*val);
    }
  }
  if (vz1){
    int i1 = i0 + 16384;
    if (vy0){
      if (vx0) atomicAdd(&vol[i1],     gx0*gy0*fz*val);
      if (vx1) atomicAdd(&vol[i1+1],   fx *gy0*fz*val);
    }
    if (vy1){
      if (vx0) atomicAdd(&vol[i1+128], gx0*fy*fz*val);
      if (vx1) atomicAdd(&vol[i1+129], fx *fy*fz*val);
    }
  }
}

// ---------------- A: gather over 27 PSF taps ----------------
__global__ void k_gather(const float* __restrict__ vol, const float* __restrict__ Rm,
                         const float* __restrict__ pw, const float* __restrict__ mask,
                         const float* __restrict__ ps, float* __restrict__ out,
                         int outStride, int outOff)
{
  int gid = blockIdx.x*256 + threadIdx.x;
  if (gid >= NSL*NPX) return;
  int n = gid >> 14, p = gid & 16383;
  int py = p >> 7, px = p & 127;
  float rm[12];
  #pragma unroll
  for (int i = 0; i < 12; i++) rm[i] = Rm[n*12 + i];
  float gx = (float)px - 63.5f, gy = (float)py - 63.5f;
  float bx = rm[0]*gx + rm[1]*gy + rm[9]  + 63.5f;
  float by = rm[3]*gx + rm[4]*gy + rm[10] + 63.5f;
  float bz = rm[6]*gx + rm[7]*gy + rm[11] + 63.5f;
  float acc = 0.f;
  #pragma unroll 1
  for (int k = 0; k < 27; k++){
    float ox = (float)(k % 3) - 1.f;
    float oy = (float)((k/3) % 3) - 1.f;
    float oz = (float)(k/9) - 1.f;
    float dx = rm[0]*ox + rm[1]*oy + rm[2]*oz;
    float dy = rm[3]*ox + rm[4]*oy + rm[5]*oz;
    float dz = rm[6]*ox + rm[7]*oy + rm[8]*oz;
    acc += pw[k] * tri_gather(vol, bx + dx, by + dy, bz + dz);
  }
  float v = acc * mask[gid];
  if (ps) v *= ps[n];
  out[n*outStride + outOff + p] = v;
}

// ---------------- At: scatter over 27 PSF taps ----------------
__global__ void k_scatter(float* __restrict__ volOut, const float* __restrict__ s,
                          const float* __restrict__ Rm, const float* __restrict__ pw,
                          const float* __restrict__ mask, const float* __restrict__ ps)
{
  int gid = blockIdx.x*256 + threadIdx.x;
  if (gid >= NSL*NPX) return;
  int n = gid >> 14, p = gid & 16383;
  float val = s[gid] * mask[gid];
  if (ps) val *= ps[n];
  if (val == 0.f) return;
  int py = p >> 7, px = p & 127;
  float rm[12];
  #pragma unroll
  for (int i = 0; i < 12; i++) rm[i] = Rm[n*12 + i];
  float gx = (float)px - 63.5f, gy = (float)py - 63.5f;
  float bx = rm[0]*gx + rm[1]*gy + rm[9]  + 63.5f;
  float by = rm[3]*gx + rm[4]*gy + rm[10] + 63.5f;
  float bz = rm[6]*gx + rm[7]*gy + rm[11] + 63.5f;
  #pragma unroll 1
  for (int k = 0; k < 27; k++){
    float ox = (float)(k % 3) - 1.f;
    float oy = (float)((k/3) % 3) - 1.f;
    float oz = (float)(k/9) - 1.f;
    float dx = rm[0]*ox + rm[1]*oy + rm[2]*oz;
    float dy = rm[3]*ox + rm[4]*oy + rm[5]*oz;
    float dz = rm[6]*ox + rm[7]*oy + rm[8]*oz;
    tri_scatter(volOut, bx + dx, by + dy, bz + dz, pw[k]*val);
  }
}

// ---------------- tiled conv (NCHW fp32, LDS-staged) ----------------
// Block: (batch-group of BPB, 16 output channels, TILE x TILE spatial tile).
// Thread: 2x2 output px, 16 co accumulators (64 VGPRs).
// BPB = 1024/TILE^2 (TILE=32 -> 1 batch/block, TILE=16 -> 4 batches/block).
template<int K, int S, int TILE, int CC>
__global__ __launch_bounds__(256, 2) void k_convt(
    const float* __restrict__ in, const float* __restrict__ wt,
    const float* __restrict__ res, float* __restrict__ out,
    int Cin, int Hin, int Cout, int Hout,
    int pad, int relu, int coTiles, int spTiles)
{
  constexpr int BPB  = 1024 / (TILE*TILE);
  constexpr int IT   = (TILE-1)*S + K;
  constexpr int KK   = K*K;
  constexpr int PERB = (TILE/2)*(TILE/2);

  __shared__ float sIn[BPB*CC*IT*IT];
  __shared__ float sW[CC*KK*16];

  int tid = threadIdx.x;
  int bl  = tid / PERB;
  int t2  = tid % PERB;
  int tx  = t2 % (TILE/2);
  int ty  = t2 / (TILE/2);

  int bid = blockIdx.x;
  int spT = bid % spTiles; bid /= spTiles;
  int coT = bid % coTiles; bid /= coTiles;
  int b0  = bid * BPB;

  int tpr = Hout / TILE;
  int ox0 = (spT % tpr) * TILE;
  int oy0 = (spT / tpr) * TILE;
  int co0 = coT * 16;
  int ix0 = ox0*S - pad;
  int iy0 = oy0*S - pad;

  float acc[64];
  #pragma unroll
  for (int i = 0; i < 64; i++) acc[i] = 0.f;

  for (int ci0 = 0; ci0 < Cin; ci0 += CC){
    // stage weights: layout sW[(cc*KK + tap)*16 + co] so co is contiguous (float4 reads)
    for (int i = tid; i < 16*CC*KK; i += 256){
      int co = i / (CC*KK);
      int r  = i % (CC*KK);
      int cc = r / KK;
      int tap= r % KK;
      sW[(cc*KK + tap)*16 + co] = wt[((size_t)(co0+co)*Cin + ci0+cc)*KK + tap];
    }
    // stage input tile(s): each batch's threads load their own tile
    for (int i = t2; i < CC*IT*IT; i += PERB){
      int cc = i / (IT*IT);
      int r  = i % (IT*IT);
      int yy = r / IT, xx = r % IT;
      int gy = iy0 + yy, gx = ix0 + xx;
      float v = 0.f;
      if ((unsigned)gy < (unsigned)Hin && (unsigned)gx < (unsigned)Hin)
        v = in[(((size_t)(b0+bl)*Cin + ci0+cc)*Hin + gy)*Hin + gx];
      sIn[((bl*CC + cc)*IT + yy)*IT + xx] = v;
    }
    __syncthreads();

    #pragma unroll
    for (int cc = 0; cc < CC; cc++){
      const float* ip = &sIn[(bl*CC + cc)*IT*IT];
      #pragma unroll
      for (int ky = 0; ky < K; ky++){
        #pragma unroll
        for (int kx = 0; kx < K; kx++){
          int y0 = (2*ty)*S + ky, x0 = (2*tx)*S + kx;
          float i00 = ip[y0*IT + x0];
          float i10 = ip[y0*IT + x0 + S];
          float i01 = ip[(y0+S)*IT + x0];
          float i11 = ip[(y0+S)*IT + x0 + S];
          const float4* wv = (const float4*)&sW[(cc*KK + ky*K + kx)*16];
          #pragma unroll
          for (int g = 0; g < 4; g++){
            float4 w = wv[g];
            acc[(g*4+0)*4+0] += w.x*i00; acc[(g*4+0)*4+1] += w.x*i10;
            acc[(g*4+0)*4+2] += w.x*i01; acc[(g*4+0)*4+3] += w.x*i11;
            acc[(g*4+1)*4+0] += w.y*i00; acc[(g*4+1)*4+1] += w.y*i10;
            acc[(g*4+1)*4+2] += w.y*i01; acc[(g*4+1)*4+3] += w.y*i11;
            acc[(g*4+2)*4+0] += w.z*i00; acc[(g*4+2)*4+1] += w.z*i10;
            acc[(g*4+2)*4+2] += w.z*i01; acc[(g*4+2)*4+3] += w.z*i11;
            acc[(g*4+3)*4+0] += w.w*i00; acc[(g*4+3)*4+1] += w.w*i10;
            acc[(g*4+3)*4+2] += w.w*i01; acc[(g*4+3)*4+3] += w.w*i11;
          }
        }
      }
    }
    __syncthreads();
  }

  int b = b0 + bl;
  #pragma unroll
  for (int co = 0; co < 16; co++){
    size_t base = (((size_t)b*Cout + co0+co)*Hout + oy0 + 2*ty)*Hout + ox0 + 2*tx;
    float v0 = acc[co*4+0], v1 = acc[co*4+1], v2 = acc[co*4+2], v3 = acc[co*4+3];
    if (res){
      v0 += res[base];        v1 += res[base+1];
      v2 += res[base+Hout];   v3 += res[base+Hout+1];
    }
    if (relu){
      v0 = fmaxf(v0,0.f); v1 = fmaxf(v1,0.f);
      v2 = fmaxf(v2,0.f); v3 = fmaxf(v3,0.f);
    }
    out[base]        = v0;  out[base+1]      = v1;
    out[base+Hout]   = v2;  out[base+Hout+1] = v3;
  }
}

// ---------------- pool + transformer ----------------
__global__ void k_pool(const float* __restrict__ in, float* __restrict__ feat, int cnt)
{
  int gid = blockIdx.x*256 + threadIdx.x;
  if (gid >= cnt) return;
  const float* p = in + (size_t)gid*256;
  float s = 0.f;
  for (int i = 0; i < 256; i++) s += p[i];
  feat[gid] = s * (1.f/256.f);
}

__global__ void k_pe(const float* __restrict__ feat, const float* __restrict__ theta,
                     const float* __restrict__ idxin, const float* __restrict__ pos_w,
                     const float* __restrict__ pos_b, float* __restrict__ hs)
{
  int gid = blockIdx.x*256 + threadIdx.x;
  if (gid >= 64*256) return;
  int n = gid >> 8, d = gid & 255;
  float s = pos_b[d];
  #pragma unroll
  for (int j = 0; j < 6; j++) s += theta[n*6+j] * pos_w[j*256+d];
  #pragma unroll
  for (int j = 0; j < 2; j++) s += idxin[n*2+j] * pos_w[(6+j)*256+d];
  hs[gid] = feat[gid] + s;
}

__global__ void k_qkv(const float* __restrict__ hs, const float* __restrict__ wq,
                      const float* __restrict__ wk, const float* __restrict__ wv,
                      float* __restrict__ qkv)
{
  int gid = blockIdx.x*256 + threadIdx.x;
  if (gid >= 64*768) return;
  int n = gid / 768, m = gid % 768;
  int which = m >> 8, j = m & 255;
  const float* w = (which == 0) ? wq : (which == 1) ? wk : wv;
  const float* h = hs + n*256;
  float s = 0.f;
  for (int i = 0; i < 256; i++) s += h[i] * w[i*256 + j];
  qkv[which*16384 + n*256 + j] = s;
}

__global__ void k_attn(const float* __restrict__ qkv, float* __restrict__ aout)
{
  int h = blockIdx.x;
  int tid = threadIdx.x;
  __shared__ float sc[4096];
  const float* q  = qkv + h*64;
  const float* kk = qkv + 16384 + h*64;
  const float* v  = qkv + 32768 + h*64;
  for (int idx = tid; idx < 4096; idx += 256){
    int qi = idx >> 6, ki = idx & 63;
    float s = 0.f;
    for (int d = 0; d < 64; d++) s += q[qi*256+d] * kk[ki*256+d];
    sc[idx] = s * 0.125f;
  }
  __syncthreads();
  if (tid < 64){
    float mx = -1e30f;
    for (int k = 0; k < 64; k++) mx = fmaxf(mx, sc[tid*64+k]);
    float sum = 0.f;
    for (int k = 0; k < 64; k++){ float e = __expf(sc[tid*64+k]-mx); sc[tid*64+k] = e; sum += e; }
    float inv = 1.f/sum;
    for (int k = 0; k < 64; k++) sc[tid*64+k] *= inv;
  }
  __syncthreads();
  for (int idx = tid; idx < 4096; idx += 256){
    int qi = idx >> 6, d = idx & 63;
    float s = 0.f;
    for (int ki = 0; ki < 64; ki++) s += sc[qi*64+ki] * v[ki*256+d];
    aout[qi*256 + h*64 + d] = s;
  }
}

__global__ void k_proj_ln(const float* __restrict__ ain, const float* __restrict__ wo,
                          const float* __restrict__ g, const float* __restrict__ bb,
                          float* __restrict__ hs)
{
  int n = blockIdx.x, d = threadIdx.x;
  __shared__ float row[256];
  __shared__ float red[256];
  __shared__ float smean, svar;
  row[d] = ain[n*256+d];
  __syncthreads();
  float s = hs[n*256+d];
  for (int i = 0; i < 256; i++) s += row[i] * wo[i*256+d];
  red[d] = s; __syncthreads();
  for (int off = 128; off; off >>= 1){ if (d < off) red[d] += red[d+off]; __syncthreads(); }
  if (d == 0) smean = red[0] * (1.f/256.f);
  __syncthreads();
  float c = s - smean;
  red[d] = c*c; __syncthreads();
  for (int off = 128; off; off >>= 1){ if (d < off) red[d] += red[d+off]; __syncthreads(); }
  if (d == 0) svar = red[0] * (1.f/256.f);
  __syncthreads();
  hs[n*256+d] = c * rsqrtf(svar + 1e-5f) * g[d] + bb[d];
}

__global__ void k_ff1(const float* __restrict__ hs, const float* __restrict__ w,
                      const float* __restrict__ b, float* __restrict__ h1)
{
  int gid = blockIdx.x*256 + threadIdx.x;
  if (gid >= 64*512) return;
  int n = gid >> 9, j = gid & 511;
  float s = b[j];
  const float* h = hs + n*256;
  for (int i = 0; i < 256; i++) s += h[i] * w[i*512 + j];
  h1[gid] = fmaxf(s, 0.f);
}

__global__ void k_ff2_ln(const float* __restrict__ h1, const float* __restrict__ w,
                         const float* __restrict__ b, const float* __restrict__ g,
                         const float* __restrict__ bb, float* __restrict__ hs)
{
  int n = blockIdx.x, d = threadIdx.x;
  __shared__ float row[512];
  __shared__ float red[256];
  __shared__ float smean, svar;
  row[d] = h1[n*512+d];
  row[d+256] = h1[n*512+256+d];
  __syncthreads();
  float s = hs[n*256+d] + b[d];
  for (int i = 0; i < 512; i++) s += row[i] * w[i*256+d];
  red[d] = s; __syncthreads();
  for (int off = 128; off; off >>= 1){ if (d < off) red[d] += red[d+off]; __syncthreads(); }
  if (d == 0) smean = red[0] * (1.f/256.f);
  __syncthreads();
  float c = s - smean;
  red[d] = c*c; __syncthreads();
  for (int off = 128; off; off >>= 1){ if (d < off) red[d] += red[d+off]; __syncthreads(); }
  if (d == 0) svar = red[0] * (1.f/256.f);
  __syncthreads();
  hs[n*256+d] = c * rsqrtf(svar + 1e-5f) * g[d] + bb[d];
}

__global__ void k_head(const float* __restrict__ hs, const float* __restrict__ fcw,
                       const float* __restrict__ fcb, float* __restrict__ pvec,
                       float* __restrict__ outx)
{
  int n = threadIdx.x; // 64 threads
  float s = fcb[0];
  const float* h = hs + n*256;
  for (int i = 0; i < 256; i++) s += h[i] * fcw[i];
  __shared__ float xs[64];
  xs[n] = s;
  __syncthreads();
  float mx = -1e30f;
  for (int i = 0; i < 64; i++) mx = fmaxf(mx, xs[i]);
  float sum = 0.f;
  for (int i = 0; i < 64; i++) sum += __expf(xs[i]-mx);
  float val = __expf(s-mx)/sum * 64.f;
  val = fminf(val, 3.f);
  pvec[n] = val;
  outx[n] = val;
}

// ---------------- CG helpers ----------------
__global__ void k_dot(const float* __restrict__ a, const float* __restrict__ b,
                      float* __restrict__ scal, int slot, int n)
{
  int gid = blockIdx.x*blockDim.x + threadIdx.x;
  int stride = gridDim.x*blockDim.x;
  float s = 0.f;
  for (int i = gid; i < n; i += stride) s += a[i]*b[i];
  for (int off = 32; off; off >>= 1) s += __shfl_down(s, off, 64);
  __shared__ float wsum[4];
  int lane = threadIdx.x & 63, wv = threadIdx.x >> 6;
  if (lane == 0) wsum[wv] = s;
  __syncthreads();
  if (threadIdx.x == 0) atomicAdd(&scal[slot], wsum[0]+wsum[1]+wsum[2]+wsum[3]);
}

__global__ void k_div(float* scal, int so, int sa, int sb)
{
  if (threadIdx.x == 0 && blockIdx.x == 0) scal[so] = scal[sa] / scal[sb];
}

__global__ void k_rinit(const float* __restrict__ b, const float* __restrict__ A,
                        float* __restrict__ r, float* __restrict__ p)
{
  int gid = blockIdx.x*256 + threadIdx.x;
  if (gid < VN){ float v = b[gid] - A[gid]; r[gid] = v; p[gid] = v; }
}

__global__ void k_xr(float* __restrict__ x, const float* __restrict__ p,
                     float* __restrict__ r, const float* __restrict__ Ap,
                     const float* __restrict__ scal, int slot)
{
  int gid = blockIdx.x*256 + threadIdx.x;
  if (gid < VN){
    float a = scal[slot];
    x[gid] += a * p[gid];
    r[gid] -= a * Ap[gid];
  }
}

__global__ void k_pupd(float* __restrict__ p, const float* __restrict__ r,
                       const float* __restrict__ scal, int slot)
{
  int gid = blockIdx.x*256 + threadIdx.x;
  if (gid < VN){ float b = scal[slot]; p[gid] = r[gid] + b * p[gid]; }
}

__global__ void k_xonly(float* __restrict__ x, const float* __restrict__ p,
                        const float* __restrict__ scal, int slot)
{
  int gid = blockIdx.x*256 + threadIdx.x;
  if (gid < VN) x[gid] += scal[slot] * p[gid];
}

__global__ void k_final(const float* __restrict__ x, float* __restrict__ out)
{
  int gid = blockIdx.x*256 + threadIdx.x;
  if (gid < VN) out[gid] = fmaxf(x[gid], 0.f);
}

// ---------------- host launch ----------------
extern "C" void kernel_launch(void* const* d_in, const int* in_sizes, int n_in,
                              void* d_out, int out_size, void* d_ws, size_t ws_size,
                              hipStream_t stream)
{
  const float* theta      = (const float*)d_in[0];
  const float* transforms = (const float*)d_in[1];
  const float* slices     = (const float*)d_in[2];
  const float* volume     = (const float*)d_in[3];
  const float* psf        = (const float*)d_in[4];
  const float* idxv       = (const float*)d_in[5];

  char* wsp = (char*)d_ws;
  auto carve = [&](size_t bytes)->void*{
    void* r = (void*)wsp; wsp += (bytes + 255) & ~(size_t)255; return r;
  };
  float* scal = (float*)carve(16*4);
  float* Rm   = (float*)carve(768*4);
  float* pw   = (float*)carve(32*4);
  float* pvec = (float*)carve(64*4);
  float* feat = (float*)carve(16384*4);
  float* hs   = (float*)carve(16384*4);
  float* qkv  = (float*)carve(49152*4);
  float* aout = (float*)carve(16384*4);
  float* h1   = (float*)carve(32768*4);
  float* mask = (float*)carve((size_t)NSL*NPX*4);
  float* volA = (float*)carve((size_t)VN*4);

  // choose conv batch-chunk CB by available workspace (same result every call)
  size_t used  = (size_t)(wsp - (char*)d_ws);
  size_t avail = (ws_size > used) ? ws_size - used : 0;
  size_t cgU   = ((size_t)4*VN + NSL*NPX)*4;               // CG overlay requirement
  auto needU = [&](int cb)->size_t{
    size_t u = ((size_t)VN + 3*(size_t)cb*262144)*4;       // z + 3 conv bufs
    return (u > cgU) ? u : cgU;
  };
  int CB = 8;
  if (avail >= needU(64) + 4096) CB = 64;
  else if (avail >= needU(32) + 4096) CB = 32;

  size_t cbe = (size_t)CB*262144;                          // conv buffer elems per chunk
  float* U    = (float*)carve(needU(CB));
  float* z    = U;
  float* bufA = U + VN;
  float* bufB = bufA + cbe;
  float* bufC = bufB + cbe;
  float* bvol = U;
  float* rvol = U + VN;
  float* pvol = U + 2*(size_t)VN;
  float* Avol = U + 3*(size_t)VN;
  float* sscr = U + 4*(size_t)VN;

  hipMemsetAsync(scal, 0, 64, stream);
  k_prep<<<1, 64, 0, stream>>>(transforms, psf, Rm, pw);
  k_mask<<<4096, 256, 0, stream>>>(slices, mask);
  k_volcopy<<<8192, 256, 0, stream>>>(volume, volA);
  k_gather<<<4096, 256, 0, stream>>>(volA, Rm, pw, mask, nullptr, z, 2*NPX, NPX);
  k_copy0<<<4096, 256, 0, stream>>>(slices, z);

  const float* w6  = (const float*)d_in[6];
  const float* w7  = (const float*)d_in[7];
  const float* w8  = (const float*)d_in[8];
  const float* w9  = (const float*)d_in[9];
  const float* w10 = (const float*)d_in[10];
  const float* w11 = (const float*)d_in[11];
  const float* w12 = (const float*)d_in[12];
  const float* w13 = (const float*)d_in[13];
  const float* w14 = (const float*)d_in[14];

  // CNN in chunks of CB slices; tiled convs
  for (int c = 0; c < 64/CB; c++){
    const float* zc = z + (size_t)c*CB*2*NPX;
    k_convt<7,2,32,2><<<CB*16, 256, 0, stream>>>(zc,  w6,  nullptr, bufA, 2,  128, 64,  64, 2, 1, 4, 4);
    k_convt<3,1,32,4><<<CB*16, 256, 0, stream>>>(bufA, w7,  nullptr, bufB, 64, 64,  64,  64, 1, 1, 4, 4);
    k_convt<3,1,32,4><<<CB*16, 256, 0, stream>>>(bufB, w8,  bufA,    bufC, 64, 64,  64,  64, 1, 1, 4, 4);
    k_convt<3,2,32,1><<<CB*8,  256, 0, stream>>>(bufC, w9,  nullptr, bufA, 64, 64,  128, 32, 0, 1, 8, 1);
    k_convt<1,2,32,2><<<CB*8,  256, 0, stream>>>(bufC, w11, nullptr, bufB, 64, 64,  128, 32, 0, 0, 8, 1);
    k_convt<3,1,32,4><<<CB*8,  256, 0, stream>>>(bufA, w10, bufB,    bufC, 128,32,  128, 32, 1, 1, 8, 1);
    k_convt<3,2,16,1><<<(CB/4)*16, 256, 0, stream>>>(bufC, w12, nullptr, bufA, 128, 32, 256, 16, 0, 1, 16, 1);
    k_convt<1,2,16,2><<<(CB/4)*16, 256, 0, stream>>>(bufC, w14, nullptr, bufB, 128, 32, 256, 16, 0, 0, 16, 1);
    k_convt<3,1,16,4><<<(CB/4)*16, 256, 0, stream>>>(bufA, w13, bufB,    bufC, 256, 16, 256, 16, 1, 1, 16, 1);
    k_pool<<<CB, 256, 0, stream>>>(bufC, feat + (size_t)c*CB*256, CB*256);
  }

  k_pe<<<64, 256, 0, stream>>>(feat, theta, idxv, (const float*)d_in[15], (const float*)d_in[16], hs);
  for (int l = 0; l < 4; l++){
    k_qkv<<<192, 256, 0, stream>>>(hs, (const float*)d_in[17] + (size_t)l*65536,
                                       (const float*)d_in[18] + (size_t)l*65536,
                                       (const float*)d_in[19] + (size_t)l*65536, qkv);
    k_attn<<<4, 256, 0, stream>>>(qkv, aout);
    k_proj_ln<<<64, 256, 0, stream>>>(aout, (const float*)d_in[20] + (size_t)l*65536,
                                      (const float*)d_in[21] + l*256, (const float*)d_in[22] + l*256, hs);
    k_ff1<<<128, 256, 0, stream>>>(hs, (const float*)d_in[23] + (size_t)l*131072,
                                   (const float*)d_in[24] + l*512, h1);
    k_ff2_ln<<<64, 256, 0, stream>>>(h1, (const float*)d_in[25] + (size_t)l*131072,
                                     (const float*)d_in[26] + l*256, (const float*)d_in[27] + l*256,
                                     (const float*)d_in[28] + l*256, hs);
  }
  k_head<<<1, 64, 0, stream>>>(hs, (const float*)d_in[29], (const float*)d_in[30], pvec,
                               (float*)d_out + VN);

  // ---- CG (union region now CG-owned) ----
  hipMemsetAsync(bvol, 0, (size_t)VN*4, stream);
  k_scatter<<<4096, 256, 0, stream>>>(bvol, slices, Rm, pw, mask, pvec);      // b = At(slices*p)
  k_gather<<<4096, 256, 0, stream>>>(volA, Rm, pw, mask, pvec, sscr, NPX, 0); // A(x0)*mask*p
  hipMemsetAsync(Avol, 0, (size_t)VN*4, stream);
  k_scatter<<<4096, 256, 0, stream>>>(Avol, sscr, Rm, pw, mask, nullptr);     // AtA(x0)
  k_rinit<<<8192, 256, 0, stream>>>(bvol, Avol, rvol, pvol);
  k_dot<<<512, 256, 0, stream>>>(rvol, rvol, scal, 0, VN);         // rr0
  // iter 1
  k_gather<<<4096, 256, 0, stream>>>(pvol, Rm, pw, mask, pvec, sscr, NPX, 0);
  hipMemsetAsync(Avol, 0, (size_t)VN*4, stream);
  k_scatter<<<4096, 256, 0, stream>>>(Avol, sscr, Rm, pw, mask, nullptr);
  k_dot<<<512, 256, 0, stream>>>(pvol, Avol, scal, 1, VN);         // pAp1
  k_div<<<1, 1, 0, stream>>>(scal, 2, 0, 1);                       // alpha1 = rr0/pAp1
  k_xr<<<8192, 256, 0, stream>>>(volA, pvol, rvol, Avol, scal, 2);
  k_dot<<<512, 256, 0, stream>>>(rvol, rvol, scal, 3, VN);         // rr1
  k_div<<<1, 1, 0, stream>>>(scal, 4, 3, 0);                       // beta = rr1/rr0
  k_pupd<<<8192, 256, 0, stream>>>(pvol, rvol, scal, 4);
  // iter 2
  k_gather<<<4096, 256, 0, stream>>>(pvol, Rm, pw, mask, pvec, sscr, NPX, 0);
  hipMemsetAsync(Avol, 0, (size_t)VN*4, stream);
  k_scatter<<<4096, 256, 0, stream>>>(Avol, sscr, Rm, pw, mask, nullptr);
  k_dot<<<512, 256, 0, stream>>>(pvol, Avol, scal, 5, VN);         // pAp2
  k_div<<<1, 1, 0, stream>>>(scal, 6, 3, 5);                       // alpha2 = rr1/pAp2
  k_xonly<<<8192, 256, 0, stream>>>(volA, pvol, scal, 6);

  k_final<<<8192, 256, 0, stream>>>(volA, (float*)d_out);
}